// Round 1
// baseline (3061.240 us; speedup 1.0000x reference)
//
#include <hip/hip_runtime.h>
#include <cmath>

// ---------------------------------------------------------------------------
// CapsNet forward, fp32 baseline.
// Shapes: B=256, conv1: [B,1,20,20]->[B,256,12,12]; prim: ->[B,256,4,4];
// routes R=512, caps C=10, Dout=16, Din=8; decoder 160->512->1024->102400.
// ---------------------------------------------------------------------------

constexpr int BATCH = 256;

enum { AM_PLAIN = 0, AM_CONV1 = 1, AM_PRIM = 2 };
enum { EPI_NONE = 0, EPI_RELU = 1, EPI_SIG = 2 };

// ---------------------------------------------------------------------------
// Generic tiled fp32 GEMM: C[M,N] = A[M,K] * B[N,K]^T  (B row-major [N][K])
// A addressing per AMODE (implicit im2col for convs). 256 threads, TM=TN=8.
// blockIdx.x = n-tile, blockIdx.y = m-tile, blockIdx.z = k-split slice.
// C is offset by z*M*N (for K-split partials; z=0 otherwise).
// ---------------------------------------------------------------------------
template <int BM, int BN, int TM, int TN, int AMODE, int EPI>
__global__ __launch_bounds__(256, 2) void gemm_k(
    const float* __restrict__ A, const float* __restrict__ Bm,
    const float* __restrict__ bias, float* __restrict__ C,
    int M, int N, int K, int k_len) {
  static_assert(TM == 8 && TN == 8, "microtile fixed at 8x8");
  constexpr int BK = 8;
  constexpr int TX = BN / TN;  // threads along n

  const int tid = threadIdx.x;
  const int tx = tid % TX;
  const int ty = tid / TX;
  const int n0 = blockIdx.x * BN;
  const int m0 = blockIdx.y * BM;
  const int k_begin = blockIdx.z * k_len;
  const int k_end = k_begin + k_len;
  C += (size_t)blockIdx.z * (size_t)M * (size_t)N;

  __shared__ float As[BK][BM + 4];
  __shared__ float Bs[BK][BN + 4];

  float acc[TM][TN] = {};

  for (int kt = k_begin; kt < k_end; kt += BK) {
    __syncthreads();
    // ---- stage A tile: BM x BK ----
    for (int base = tid * 4; base < BM * BK; base += 1024) {
      int ml = base / BK;
      int kl = base % BK;
#pragma unroll
      for (int j = 0; j < 4; j++) {
        int k = kt + kl + j;
        float v = 0.f;
        if (k < k_end) {
          if constexpr (AMODE == AM_PLAIN) {
            v = A[(size_t)(m0 + ml) * K + k];
          } else if constexpr (AMODE == AM_CONV1) {
            // m=(b,p) p=py*12+px ; k=ky*9+kx ; data [B,20,20]
            int m = m0 + ml;
            int b = m / 144, p = m - b * 144;
            int py = p / 12, px = p - py * 12;
            int ky = k / 9, kx = k - ky * 9;
            v = A[b * 400 + (py + ky) * 20 + (px + kx)];
          } else {
            // m=(b,q) q=y*4+x ; k=kk*256+cin, kk=ky*9+kx ; A=h [B,144,256]
            int m = m0 + ml;
            int b = m >> 4, q = m & 15;
            int y = q >> 2, xx = q & 3;
            int kk = k >> 8, cin = k & 255;
            int ky = kk / 9, kx = kk - ky * 9;
            v = A[((b * 144) + (y + ky) * 12 + (xx + kx)) * 256 + cin];
          }
        }
        As[kl + j][ml] = v;
      }
    }
    // ---- stage B tile: BN x BK ----
    for (int base = tid * 4; base < BN * BK; base += 1024) {
      int nl = base / BK;
      int kl = base % BK;
#pragma unroll
      for (int j = 0; j < 4; j++) {
        int k = kt + kl + j;
        float v = 0.f;
        if (k < k_end) v = Bm[(size_t)(n0 + nl) * K + k];
        Bs[kl + j][nl] = v;
      }
    }
    __syncthreads();
    // ---- inner product ----
#pragma unroll
    for (int kk = 0; kk < BK; kk++) {
      float af[TM], bf[TN];
      const float4* ap = reinterpret_cast<const float4*>(&As[kk][ty * TM]);
      reinterpret_cast<float4*>(af)[0] = ap[0];
      reinterpret_cast<float4*>(af)[1] = ap[1];
      const float4* bp = reinterpret_cast<const float4*>(&Bs[kk][tx * TN]);
      reinterpret_cast<float4*>(bf)[0] = bp[0];
      reinterpret_cast<float4*>(bf)[1] = bp[1];
#pragma unroll
      for (int i = 0; i < TM; i++)
#pragma unroll
        for (int j = 0; j < TN; j++) acc[i][j] += af[i] * bf[j];
    }
  }

  // ---- epilogue ----
#pragma unroll
  for (int i = 0; i < TM; i++) {
    int m = m0 + ty * TM + i;
#pragma unroll
    for (int j = 0; j < TN; j++) {
      int n = n0 + tx * TN + j;
      float v = acc[i][j];
      if constexpr (EPI == EPI_RELU) {
        v += bias[n];
        v = fmaxf(v, 0.f);
      } else if constexpr (EPI == EPI_SIG) {
        v += bias[n];
        v = 1.f / (1.f + expf(-v));
      }
      C[(size_t)m * N + n] = v;
    }
  }
}

// ---------------------------------------------------------------------------
// prim_w [n][cin][81] -> wT [n][kk][cin]  (so GEMM B-tiles are k-contiguous)
// ---------------------------------------------------------------------------
__global__ void transpose_w_k(const float* __restrict__ w, float* __restrict__ wT) {
  int idx = blockIdx.x * 256 + threadIdx.x;
  if (idx >= 256 * 20736) return;
  int n = idx / 20736;
  int rem = idx - n * 20736;
  int kk = rem >> 8;
  int cin = rem & 255;
  wT[idx] = w[n * 20736 + cin * 81 + kk];
}

// ---------------------------------------------------------------------------
// Reduce K-split partials + bias -> u[b][ch][q], squash over capsule dim,
// scatter to x[b][r][i].  grid (16 chgroups, 256 b), 256 threads.
// r = (ch/32)*64 + (ch%32)*2 + t,  q = 8t + i.
// ---------------------------------------------------------------------------
__global__ void red_squash_k(const float* __restrict__ part,
                             const float* __restrict__ prim_b,
                             float* __restrict__ x) {
  const int chg = blockIdx.x;
  const int b = blockIdx.y;
  const int tid = threadIdx.x;
  const int ch_l = tid & 15;
  const int q = tid >> 4;
  const int ch = chg * 16 + ch_l;

  float val = prim_b[ch];
#pragma unroll
  for (int z = 0; z < 8; z++) val += part[z * 1048576 + (b * 16 + q) * 256 + ch];

  __shared__ float su[16][17];
  su[q][ch_l] = val;
  __syncthreads();

  const int vec = tid >> 3;  // 0..31 : (ch_l2, t)
  const int i = tid & 7;
  const int ch_l2 = vec >> 1;
  const int t = vec & 1;
  float sn = 0.f;
#pragma unroll
  for (int ii = 0; ii < 8; ii++) {
    float e = su[8 * t + ii][ch_l2];
    sn += e * e;
  }
  float factor = sn / ((1.f + sn) * sqrtf(sn));
  float e = su[8 * t + i][ch_l2];
  int chh = chg * 16 + ch_l2;
  int d8 = chh >> 5, d32 = chh & 31;
  int r = d8 * 64 + d32 * 2 + t;
  x[b * 4096 + r * 8 + i] = e * factor;
}

// ---------------------------------------------------------------------------
// u_hat[b,r,co] = sum_i W[r,co,i] * x[b,r,i].  one block per r.
// ---------------------------------------------------------------------------
__global__ void uhat_k(const float* __restrict__ W, const float* __restrict__ x,
                       float* __restrict__ uhat) {
  const int r = blockIdx.x;
  const int tid = threadIdx.x;
  __shared__ float Wl[8 * 160];   // [i][co]
  __shared__ float xl[256 * 8];   // [b][i]
  for (int t = tid; t < 1280; t += 256) {
    int co = t >> 3, i = t & 7;
    Wl[i * 160 + co] = W[r * 1280 + t];
  }
  for (int t = tid; t < 2048; t += 256) {
    int b = t >> 3, i = t & 7;
    xl[t] = x[b * 4096 + r * 8 + i];
  }
  __syncthreads();
  for (int item = tid; item < 256 * 160; item += 256) {
    int b = item / 160;
    int co = item - b * 160;
    float acc = 0.f;
#pragma unroll
    for (int i = 0; i < 8; i++) acc += Wl[i * 160 + co] * xl[b * 8 + i];
    uhat[b * 81920 + r * 160 + co] = acc;
  }
}

__global__ void zero_b_k(float* __restrict__ bij) {
  int id = blockIdx.x * 256 + threadIdx.x;
  if (id < 5120) bij[id] = 0.f;
}

// ---------------------------------------------------------------------------
// One routing iteration for one batch element b (block):
//  s[co] = sum_r c[r, co/16] * uhat[b,r,co]; v = elementwise squash(s);
//  if update: a[r,c] = sum_o uhat[b,r,c,o] v[c,o]  -> a_buf[b]
// ---------------------------------------------------------------------------
__global__ void route_iter_k(const float* __restrict__ uhat,
                             const float* __restrict__ c_rc,
                             float* __restrict__ v_out,
                             float* __restrict__ a_buf,
                             int use_uniform, int do_update) {
  const int b = blockIdx.x;
  const int tid = threadIdx.x;
  __shared__ float c_l[5120];
  __shared__ float v_l[160];
  if (!use_uniform) {
    for (int t = tid; t < 5120; t += 256) c_l[t] = c_rc[t];
  }
  __syncthreads();
  if (tid < 160) {
    const float* up = uhat + b * 81920 + tid;
    const int cls = tid >> 4;
    float acc = 0.f;
    if (use_uniform) {
#pragma unroll 8
      for (int r = 0; r < 512; r++) acc += up[r * 160];
      acc *= (1.f / 512.f);
    } else {
#pragma unroll 8
      for (int r = 0; r < 512; r++) acc += c_l[r * 10 + cls] * up[r * 160];
    }
    float sq = acc * acc;
    float vv = sq * acc / ((1.f + sq) * sqrtf(sq));
    v_l[tid] = vv;
    v_out[b * 160 + tid] = vv;
  }
  __syncthreads();
  if (do_update) {
    for (int item = tid; item < 5120; item += 256) {
      int r = item / 10;
      int c = item - r * 10;
      const float* up2 = uhat + b * 81920 + r * 160 + c * 16;
      float a = 0.f;
#pragma unroll
      for (int o = 0; o < 16; o++) a += up2[o] * v_l[c * 16 + o];
      a_buf[b * 5120 + item] = a;
    }
  }
}

// b_ij[rc] += mean_b a[b,rc]
__global__ void bupd_k(const float* __restrict__ a_buf, float* __restrict__ bij) {
  int id = blockIdx.x * 256 + threadIdx.x;
  if (id >= 5120) return;
  float s = 0.f;
  for (int b = 0; b < BATCH; b++) s += a_buf[b * 5120 + id];
  bij[id] += s * (1.f / 256.f);
}

// c[r,c] = softmax over routes axis of b_ij
__global__ void softmax_b_k(const float* __restrict__ bij, float* __restrict__ c_rc) {
  const int tid = threadIdx.x;
  __shared__ float Ml[10], Sl[10];
  if (tid < 10) {
    float m = -1e30f;
    for (int r = 0; r < 512; r++) m = fmaxf(m, bij[r * 10 + tid]);
    float s = 0.f;
    for (int r = 0; r < 512; r++) s += expf(bij[r * 10 + tid] - m);
    Ml[tid] = m;
    Sl[tid] = s;
  }
  __syncthreads();
  if (tid < 512) {
    for (int c = 0; c < 10; c++)
      c_rc[tid * 10 + c] = expf(bij[tid * 10 + c] - Ml[c]) / Sl[c];
  }
}

// ---------------------------------------------------------------------------
// classes = softmax over BATCH axis of capsule norms; argmax over classes
// (first max, like jnp.argmax); sel[b] = chosen 16-dim capsule.
// Single block, 256 threads (one per b).
// ---------------------------------------------------------------------------
__global__ void classes_k(const float* __restrict__ v, float* __restrict__ sel,
                          int* __restrict__ idxb) {
  const int b = threadIdx.x;
  float cl[10], ex[10];
  for (int c = 0; c < 10; c++) {
    float s = 0.f;
    for (int o = 0; o < 16; o++) {
      float e = v[b * 160 + c * 16 + o];
      s += e * e;
    }
    cl[c] = sqrtf(s);
  }
  __shared__ float red[256];
  __shared__ float Mc[10], Sc[10];
  for (int c = 0; c < 10; c++) {
    red[b] = cl[c];
    __syncthreads();
    for (int s = 128; s > 0; s >>= 1) {
      if (b < s) red[b] = fmaxf(red[b], red[b + s]);
      __syncthreads();
    }
    if (b == 0) Mc[c] = red[0];
    __syncthreads();
  }
  for (int c = 0; c < 10; c++) {
    ex[c] = expf(cl[c] - Mc[c]);
    red[b] = ex[c];
    __syncthreads();
    for (int s = 128; s > 0; s >>= 1) {
      if (b < s) red[b] += red[b + s];
      __syncthreads();
    }
    if (b == 0) Sc[c] = red[0];
    __syncthreads();
  }
  float best = ex[0] / Sc[0];
  int bi = 0;
  for (int c = 1; c < 10; c++) {
    float p = ex[c] / Sc[c];
    if (p > best) { best = p; bi = c; }
  }
  idxb[b] = bi;
  for (int o = 0; o < 16; o++) sel[b * 16 + o] = v[b * 160 + bi * 16 + o];
}

// h1[b,j] = relu(b1[j] + sum_o sel[b,o] * w1[j, idx*16+o])
__global__ void h1_k(const float* __restrict__ sel, const int* __restrict__ idxb,
                     const float* __restrict__ w1, const float* __restrict__ b1,
                     float* __restrict__ h1) {
  const int b = blockIdx.x;
  const int j = threadIdx.x;
  __shared__ float ssel[16];
  __shared__ int six;
  if (j < 16) ssel[j] = sel[b * 16 + j];
  if (j == 0) six = idxb[b];
  __syncthreads();
  const float* wrow = w1 + j * 160 + six * 16;
  float acc = b1[j];
#pragma unroll
  for (int o = 0; o < 16; o++) acc += ssel[o] * wrow[o];
  h1[b * 512 + j] = fmaxf(acc, 0.f);
}

// ---------------------------------------------------------------------------
// ws layout (floats). Peak = 35,717,120 floats = 142.9 MB.
//   [0, 20971520)            u_hat     (aliases prim-GEMM partials [0, 8388608))
//   [20971520, 30408704)     h [B,144,256]   (dead after prim GEMM)
//   [30408704, 35717120)     wT              (dead after prim GEMM)
//   post-conv small buffers overlay the dead h region:
//   x     @ 20971520  (1048576)
//   v     @ 22020096  (40960)
//   b_ij  @ 22061056  (5120)
//   c_rc  @ 22066176  (5120)
//   a_buf @ 22071296  (1310720)
//   sel   @ 23382016  (4096)
//   idx   @ 23386112  (256, int)
//   h1    @ 23386368  (131072)
//   h2    @ 23517440  (262144)
// ---------------------------------------------------------------------------
extern "C" void kernel_launch(void* const* d_in, const int* in_sizes, int n_in,
                              void* d_out, int out_size, void* d_ws, size_t ws_size,
                              hipStream_t stream) {
  const float* data    = (const float*)d_in[0];
  const float* conv1_w = (const float*)d_in[1];
  const float* conv1_b = (const float*)d_in[2];
  const float* prim_w  = (const float*)d_in[3];
  const float* prim_b  = (const float*)d_in[4];
  const float* W_digit = (const float*)d_in[5];
  const float* dec_w1  = (const float*)d_in[6];
  const float* dec_b1  = (const float*)d_in[7];
  const float* dec_w2  = (const float*)d_in[8];
  const float* dec_b2  = (const float*)d_in[9];
  const float* dec_w3  = (const float*)d_in[10];
  const float* dec_b3  = (const float*)d_in[11];
  float* out = (float*)d_out;

  float* ws = (float*)d_ws;
  float* uhat = ws;
  float* part = ws;  // alias, dead before uhat is written
  float* h    = ws + 20971520;
  float* wT   = ws + 30408704;
  float* x    = ws + 20971520;  // overlays dead h
  float* v    = ws + 22020096;
  float* bij  = ws + 22061056;
  float* crc  = ws + 22066176;
  float* abuf = ws + 22071296;
  float* sel  = ws + 23382016;
  int*   idxb = (int*)(ws + 23386112);
  float* h1   = ws + 23386368;
  float* h2   = ws + 23517440;

  // 1. transpose prim weights for k-contiguous B-tiles
  transpose_w_k<<<20736, 256, 0, stream>>>(prim_w, wT);

  // 2. conv1 as implicit GEMM: M=36864, N=256, K=81, relu+bias -> h[B,144,256]
  gemm_k<128, 128, 8, 8, AM_CONV1, EPI_RELU>
      <<<dim3(2, 288, 1), 256, 0, stream>>>(data, conv1_w, conv1_b, h,
                                            36864, 256, 81, 81);

  // 3. primary-caps conv as implicit GEMM: M=4096, N=256, K=20736, split 8
  gemm_k<128, 128, 8, 8, AM_PRIM, EPI_NONE>
      <<<dim3(2, 32, 8), 256, 0, stream>>>(h, wT, nullptr, part,
                                           4096, 256, 20736, 2592);

  // 4. reduce partials + bias, squash, gather -> x[B,512,8]
  red_squash_k<<<dim3(16, 256), 256, 0, stream>>>(part, prim_b, x);

  // 5. u_hat[b,r,10,16]
  uhat_k<<<512, 256, 0, stream>>>(W_digit, x, uhat);

  // 6. routing (3 iterations, batch-shared b_ij)
  zero_b_k<<<20, 256, 0, stream>>>(bij);
  route_iter_k<<<256, 256, 0, stream>>>(uhat, crc, v, abuf, 1, 1);
  bupd_k<<<20, 256, 0, stream>>>(abuf, bij);
  softmax_b_k<<<1, 512, 0, stream>>>(bij, crc);
  route_iter_k<<<256, 256, 0, stream>>>(uhat, crc, v, abuf, 0, 1);
  bupd_k<<<20, 256, 0, stream>>>(abuf, bij);
  softmax_b_k<<<1, 512, 0, stream>>>(bij, crc);
  route_iter_k<<<256, 256, 0, stream>>>(uhat, crc, v, nullptr, 0, 0);

  // 7. classes softmax(axis=0) + argmax + mask
  classes_k<<<1, 256, 0, stream>>>(v, sel, idxb);

  // 8. decoder
  h1_k<<<256, 512, 0, stream>>>(sel, idxb, dec_w1, dec_b1, h1);
  gemm_k<128, 128, 8, 8, AM_PLAIN, EPI_RELU>
      <<<dim3(8, 2, 1), 256, 0, stream>>>(h1, dec_w2, dec_b2, h2,
                                          256, 1024, 512, 512);
  gemm_k<256, 64, 8, 8, AM_PLAIN, EPI_SIG>
      <<<dim3(1600, 1, 1), 256, 0, stream>>>(h2, dec_w3, dec_b3, out,
                                             256, 102400, 1024, 1024);
}

// Round 2
// 1571.759 us; speedup vs baseline: 1.9477x; 1.9477x over previous
//
#include <hip/hip_runtime.h>
#include <cmath>

// ---------------------------------------------------------------------------
// CapsNet forward. Round 2: MFMA (bf16) for the two big GEMMs.
//  - prim-caps conv: split-bf16 (hi/lo, 3 products) -> ~fp32 precision, safe
//    for the downstream argmax.
//  - decoder layer 3: plain bf16 (post-argmax, sigmoid output, 1e-2 thresh).
// Everything else stays fp32.
// ---------------------------------------------------------------------------

constexpr int BATCH = 256;

enum { AM_PLAIN = 0, AM_CONV1 = 1 };
enum { EPI_NONE = 0, EPI_RELU = 1, EPI_SIG = 2, EPI_RELU_SPLIT = 3 };

typedef short bf16x8 __attribute__((ext_vector_type(8)));
typedef float f32x4 __attribute__((ext_vector_type(4)));

__device__ __forceinline__ unsigned short f2b(float v) {
  unsigned int u = __float_as_uint(v);
  u += 0x7FFFu + ((u >> 16) & 1u);
  return (unsigned short)(u >> 16);
}
__device__ __forceinline__ void split_bf(float v, unsigned short& h, unsigned short& l) {
  h = f2b(v);
  l = f2b(v - __uint_as_float(((unsigned int)h) << 16));
}

// ---------------------------------------------------------------------------
// fp32 tiled GEMM (kept for conv1 and dec2): C[M,N] = A[M,K] * B[N,K]^T
// ---------------------------------------------------------------------------
template <int BM, int BN, int TM, int TN, int AMODE, int EPI>
__global__ __launch_bounds__(256, 2) void gemm_k(
    const float* __restrict__ A, const float* __restrict__ Bm,
    const float* __restrict__ bias, float* __restrict__ C,
    int M, int N, int K, int k_len,
    unsigned short* __restrict__ Chi, unsigned short* __restrict__ Clo) {
  static_assert(TM == 8 && TN == 8, "microtile fixed at 8x8");
  constexpr int BK = 8;
  constexpr int TX = BN / TN;

  const int tid = threadIdx.x;
  const int tx = tid % TX;
  const int ty = tid / TX;
  const int n0 = blockIdx.x * BN;
  const int m0 = blockIdx.y * BM;
  const int k_begin = blockIdx.z * k_len;
  const int k_end = k_begin + k_len;
  C += (size_t)blockIdx.z * (size_t)M * (size_t)N;

  __shared__ float As[BK][BM + 4];
  __shared__ float Bs[BK][BN + 4];

  float acc[TM][TN] = {};

  for (int kt = k_begin; kt < k_end; kt += BK) {
    __syncthreads();
    for (int base = tid * 4; base < BM * BK; base += 1024) {
      int ml = base / BK;
      int kl = base % BK;
#pragma unroll
      for (int j = 0; j < 4; j++) {
        int k = kt + kl + j;
        float v = 0.f;
        if (k < k_end) {
          if constexpr (AMODE == AM_PLAIN) {
            v = A[(size_t)(m0 + ml) * K + k];
          } else {
            int m = m0 + ml;
            int b = m / 144, p = m - b * 144;
            int py = p / 12, px = p - py * 12;
            int ky = k / 9, kx = k - ky * 9;
            v = A[b * 400 + (py + ky) * 20 + (px + kx)];
          }
        }
        As[kl + j][ml] = v;
      }
    }
    for (int base = tid * 4; base < BN * BK; base += 1024) {
      int nl = base / BK;
      int kl = base % BK;
#pragma unroll
      for (int j = 0; j < 4; j++) {
        int k = kt + kl + j;
        float v = 0.f;
        if (k < k_end) v = Bm[(size_t)(n0 + nl) * K + k];
        Bs[kl + j][nl] = v;
      }
    }
    __syncthreads();
#pragma unroll
    for (int kk = 0; kk < BK; kk++) {
      float af[TM], bf[TN];
      const float4* ap = reinterpret_cast<const float4*>(&As[kk][ty * TM]);
      reinterpret_cast<float4*>(af)[0] = ap[0];
      reinterpret_cast<float4*>(af)[1] = ap[1];
      const float4* bp = reinterpret_cast<const float4*>(&Bs[kk][tx * TN]);
      reinterpret_cast<float4*>(bf)[0] = bp[0];
      reinterpret_cast<float4*>(bf)[1] = bp[1];
#pragma unroll
      for (int i = 0; i < TM; i++)
#pragma unroll
        for (int j = 0; j < TN; j++) acc[i][j] += af[i] * bf[j];
    }
  }

#pragma unroll
  for (int i = 0; i < TM; i++) {
    int m = m0 + ty * TM + i;
#pragma unroll
    for (int j = 0; j < TN; j++) {
      int n = n0 + tx * TN + j;
      float v = acc[i][j];
      if constexpr (EPI == EPI_RELU) {
        v += bias[n];
        v = fmaxf(v, 0.f);
        C[(size_t)m * N + n] = v;
      } else if constexpr (EPI == EPI_SIG) {
        v += bias[n];
        v = 1.f / (1.f + expf(-v));
        C[(size_t)m * N + n] = v;
      } else if constexpr (EPI == EPI_RELU_SPLIT) {
        v += bias[n];
        v = fmaxf(v, 0.f);
        unsigned short hs, ls;
        split_bf(v, hs, ls);
        Chi[(size_t)m * N + n] = hs;
        Clo[(size_t)m * N + n] = ls;
      } else {
        C[(size_t)m * N + n] = v;
      }
    }
  }
}

// ---------------------------------------------------------------------------
// prim_w [n][cin][81] -> wT_hi/lo [n][kk*256+cin] (bf16 split)
// ---------------------------------------------------------------------------
__global__ void transpose_w_k(const float* __restrict__ w,
                              unsigned short* __restrict__ hi,
                              unsigned short* __restrict__ lo) {
  int idx = blockIdx.x * 256 + threadIdx.x;
  if (idx >= 256 * 20736) return;
  int n = idx / 20736;
  int rem = idx - n * 20736;
  int kk = rem >> 8;
  int cin = rem & 255;
  float v = w[n * 20736 + cin * 81 + kk];
  unsigned short h, l;
  split_bf(v, h, l);
  hi[idx] = h;
  lo[idx] = l;
}

// ---------------------------------------------------------------------------
// Primary-caps conv as split-bf16 MFMA implicit GEMM.
// M=4096 (b*16+q), N=256 (ch), K=20736 (kk*256+cin). K-split 8 -> partials.
// Block: 128x128 tile, 4 waves (2x2), each wave 64x64 via 4x4 MFMA 16x16x32.
// Per K-stage (BK=32): kk is uniform; rows are contiguous 32-elem runs of h.
// C = Ahi*Bhi + Ahi*Blo + Alo*Bhi  (drop lo*lo, ~2^-18 rel err).
// ---------------------------------------------------------------------------
__global__ __launch_bounds__(256, 2) void prim_mfma_k(
    const unsigned short* __restrict__ Ahi, const unsigned short* __restrict__ Alo,
    const unsigned short* __restrict__ Bhi, const unsigned short* __restrict__ Blo,
    float* __restrict__ part) {
  constexpr int LDT = 40;  // LDS row stride (32 + 8 pad), ushorts
  __shared__ unsigned short Ah[128 * LDT], Al[128 * LDT];
  __shared__ unsigned short Bh[128 * LDT], Bl[128 * LDT];

  const int tid = threadIdx.x;
  const int wave = tid >> 6, lane = tid & 63;
  const int wm = (wave >> 1) * 64, wn = (wave & 1) * 64;
  const int cl = lane & 15, rq = lane >> 4;
  const int n0 = blockIdx.x * 128;
  const int m0 = blockIdx.y * 128;
  const int z = blockIdx.z;
  const int k_begin = z * 2592, k_end = k_begin + 2592;

  f32x4 acc[4][4];
#pragma unroll
  for (int i = 0; i < 4; i++)
#pragma unroll
    for (int j = 0; j < 4; j++) acc[i][j] = f32x4{0.f, 0.f, 0.f, 0.f};

  for (int kt = k_begin; kt < k_end; kt += 32) {
    const int kk = kt >> 8;
    const int cin0 = kt & 255;
    const int dy = kk / 9, dx = kk - dy * 9;
    __syncthreads();
#pragma unroll
    for (int j = 0; j < 4; j++) {
      int idx = j * 256 + tid;     // 1024 ushort4 slots per array
      int row = idx >> 3, c = idx & 7;
      // A: im2col of h
      int m = m0 + row;
      int b = m >> 4, q = m & 15;
      int y = q >> 2, xx = q & 3;
      size_t ga = ((size_t)(b * 144 + (y + dy) * 12 + (xx + dx)) << 8) + cin0 + c * 4;
      *(ushort4*)&Ah[row * LDT + c * 4] = *(const ushort4*)(Ahi + ga);
      *(ushort4*)&Al[row * LDT + c * 4] = *(const ushort4*)(Alo + ga);
      // B: wT rows
      size_t gb = (size_t)(n0 + row) * 20736 + kt + c * 4;
      *(ushort4*)&Bh[row * LDT + c * 4] = *(const ushort4*)(Bhi + gb);
      *(ushort4*)&Bl[row * LDT + c * 4] = *(const ushort4*)(Blo + gb);
    }
    __syncthreads();

    bf16x8 a_hi[4], b_hi[4], t[4];
#pragma unroll
    for (int im = 0; im < 4; im++)
      a_hi[im] = *(const bf16x8*)&Ah[(wm + im * 16 + cl) * LDT + rq * 8];
#pragma unroll
    for (int in = 0; in < 4; in++)
      b_hi[in] = *(const bf16x8*)&Bh[(wn + in * 16 + cl) * LDT + rq * 8];
#pragma unroll
    for (int im = 0; im < 4; im++)
#pragma unroll
      for (int in = 0; in < 4; in++)
        acc[im][in] = __builtin_amdgcn_mfma_f32_16x16x32_bf16(a_hi[im], b_hi[in],
                                                              acc[im][in], 0, 0, 0);
#pragma unroll
    for (int in = 0; in < 4; in++)
      t[in] = *(const bf16x8*)&Bl[(wn + in * 16 + cl) * LDT + rq * 8];
#pragma unroll
    for (int im = 0; im < 4; im++)
#pragma unroll
      for (int in = 0; in < 4; in++)
        acc[im][in] = __builtin_amdgcn_mfma_f32_16x16x32_bf16(a_hi[im], t[in],
                                                              acc[im][in], 0, 0, 0);
#pragma unroll
    for (int im = 0; im < 4; im++)
      t[im] = *(const bf16x8*)&Al[(wm + im * 16 + cl) * LDT + rq * 8];
#pragma unroll
    for (int im = 0; im < 4; im++)
#pragma unroll
      for (int in = 0; in < 4; in++)
        acc[im][in] = __builtin_amdgcn_mfma_f32_16x16x32_bf16(t[im], b_hi[in],
                                                              acc[im][in], 0, 0, 0);
  }

  float* Cp = part + (size_t)z * 1048576;
#pragma unroll
  for (int in = 0; in < 4; in++) {
    int n = n0 + wn + in * 16 + cl;
#pragma unroll
    for (int im = 0; im < 4; im++)
#pragma unroll
      for (int r = 0; r < 4; r++) {
        int m = m0 + wm + im * 16 + rq * 4 + r;
        Cp[(size_t)m * 256 + n] = acc[im][in][r];
      }
  }
}

// ---------------------------------------------------------------------------
// Decoder layer 3 as bf16 MFMA: out[256,102400] = sigmoid(h2 @ w3^T + b3).
// fp32 inputs converted to bf16 during LDS staging. 128x128 tile, BK=64.
// ---------------------------------------------------------------------------
__global__ __launch_bounds__(256, 2) void dec3_mfma_k(
    const float* __restrict__ A,   // h2 [256][1024]
    const float* __restrict__ Bw,  // w3 [102400][1024]
    const float* __restrict__ bias,
    float* __restrict__ C) {
  constexpr int K = 1024, N = 102400;
  constexpr int LDT = 72;  // 64 + 8 pad, ushorts
  __shared__ unsigned short As[128 * LDT];
  __shared__ unsigned short Bs[128 * LDT];

  const int tid = threadIdx.x;
  const int wave = tid >> 6, lane = tid & 63;
  const int wm = (wave >> 1) * 64, wn = (wave & 1) * 64;
  const int cl = lane & 15, rq = lane >> 4;
  const int n0 = blockIdx.x * 128;
  const int m0 = blockIdx.y * 128;

  f32x4 acc[4][4];
#pragma unroll
  for (int i = 0; i < 4; i++)
#pragma unroll
    for (int j = 0; j < 4; j++) acc[i][j] = f32x4{0.f, 0.f, 0.f, 0.f};

  for (int kt = 0; kt < K; kt += 64) {
    __syncthreads();
#pragma unroll
    for (int j = 0; j < 8; j++) {
      int idx = j * 256 + tid;     // 2048 float4 slots
      int row = idx >> 4, c4 = idx & 15;
      float4 va = *(const float4*)(A + (size_t)(m0 + row) * K + kt + c4 * 4);
      ushort4 ha;
      ha.x = f2b(va.x); ha.y = f2b(va.y); ha.z = f2b(va.z); ha.w = f2b(va.w);
      *(ushort4*)&As[row * LDT + c4 * 4] = ha;
      float4 vb = *(const float4*)(Bw + (size_t)(n0 + row) * K + kt + c4 * 4);
      ushort4 hb;
      hb.x = f2b(vb.x); hb.y = f2b(vb.y); hb.z = f2b(vb.z); hb.w = f2b(vb.w);
      *(ushort4*)&Bs[row * LDT + c4 * 4] = hb;
    }
    __syncthreads();
#pragma unroll
    for (int ko = 0; ko < 64; ko += 32) {
      bf16x8 af[4], bf[4];
#pragma unroll
      for (int im = 0; im < 4; im++)
        af[im] = *(const bf16x8*)&As[(wm + im * 16 + cl) * LDT + ko + rq * 8];
#pragma unroll
      for (int in = 0; in < 4; in++)
        bf[in] = *(const bf16x8*)&Bs[(wn + in * 16 + cl) * LDT + ko + rq * 8];
#pragma unroll
      for (int im = 0; im < 4; im++)
#pragma unroll
        for (int in = 0; in < 4; in++)
          acc[im][in] = __builtin_amdgcn_mfma_f32_16x16x32_bf16(af[im], bf[in],
                                                                acc[im][in], 0, 0, 0);
    }
  }

#pragma unroll
  for (int in = 0; in < 4; in++) {
    int n = n0 + wn + in * 16 + cl;
    float bn = bias[n];
#pragma unroll
    for (int im = 0; im < 4; im++)
#pragma unroll
      for (int r = 0; r < 4; r++) {
        int m = m0 + wm + im * 16 + rq * 4 + r;
        float v = acc[im][in][r] + bn;
        v = 1.f / (1.f + expf(-v));
        C[(size_t)m * N + n] = v;
      }
  }
}

// ---------------------------------------------------------------------------
// Reduce K-split partials + bias, squash over 8-dim capsule, scatter to x.
// ---------------------------------------------------------------------------
__global__ void red_squash_k(const float* __restrict__ part,
                             const float* __restrict__ prim_b,
                             float* __restrict__ x) {
  const int chg = blockIdx.x;
  const int b = blockIdx.y;
  const int tid = threadIdx.x;
  const int ch_l = tid & 15;
  const int q = tid >> 4;
  const int ch = chg * 16 + ch_l;

  float val = prim_b[ch];
#pragma unroll
  for (int z = 0; z < 8; z++) val += part[z * 1048576 + (b * 16 + q) * 256 + ch];

  __shared__ float su[16][17];
  su[q][ch_l] = val;
  __syncthreads();

  const int vec = tid >> 3;
  const int i = tid & 7;
  const int ch_l2 = vec >> 1;
  const int t = vec & 1;
  float sn = 0.f;
#pragma unroll
  for (int ii = 0; ii < 8; ii++) {
    float e = su[8 * t + ii][ch_l2];
    sn += e * e;
  }
  float factor = sn / ((1.f + sn) * sqrtf(sn));
  float e = su[8 * t + i][ch_l2];
  int chh = chg * 16 + ch_l2;
  int d8 = chh >> 5, d32 = chh & 31;
  int r = d8 * 64 + d32 * 2 + t;
  x[b * 4096 + r * 8 + i] = e * factor;
}

// u_hat[b,r,co] = sum_i W[r,co,i] * x[b,r,i].  one block per r.
__global__ void uhat_k(const float* __restrict__ W, const float* __restrict__ x,
                       float* __restrict__ uhat) {
  const int r = blockIdx.x;
  const int tid = threadIdx.x;
  __shared__ float Wl[8 * 160];
  __shared__ float xl[256 * 8];
  for (int t = tid; t < 1280; t += 256) {
    int co = t >> 3, i = t & 7;
    Wl[i * 160 + co] = W[r * 1280 + t];
  }
  for (int t = tid; t < 2048; t += 256) {
    int b = t >> 3, i = t & 7;
    xl[t] = x[b * 4096 + r * 8 + i];
  }
  __syncthreads();
  for (int item = tid; item < 256 * 160; item += 256) {
    int b = item / 160;
    int co = item - b * 160;
    float acc = 0.f;
#pragma unroll
    for (int i = 0; i < 8; i++) acc += Wl[i * 160 + co] * xl[b * 8 + i];
    uhat[b * 81920 + r * 160 + co] = acc;
  }
}

__global__ void zero_b_k(float* __restrict__ bij) {
  int id = blockIdx.x * 256 + threadIdx.x;
  if (id < 5120) bij[id] = 0.f;
}

__global__ void route_iter_k(const float* __restrict__ uhat,
                             const float* __restrict__ c_rc,
                             float* __restrict__ v_out,
                             float* __restrict__ a_buf,
                             int use_uniform, int do_update) {
  const int b = blockIdx.x;
  const int tid = threadIdx.x;
  __shared__ float c_l[5120];
  __shared__ float v_l[160];
  if (!use_uniform) {
    for (int t = tid; t < 5120; t += 256) c_l[t] = c_rc[t];
  }
  __syncthreads();
  if (tid < 160) {
    const float* up = uhat + b * 81920 + tid;
    const int cls = tid >> 4;
    float acc = 0.f;
    if (use_uniform) {
#pragma unroll 8
      for (int r = 0; r < 512; r++) acc += up[r * 160];
      acc *= (1.f / 512.f);
    } else {
#pragma unroll 8
      for (int r = 0; r < 512; r++) acc += c_l[r * 10 + cls] * up[r * 160];
    }
    float sq = acc * acc;
    float vv = sq * acc / ((1.f + sq) * sqrtf(sq));
    v_l[tid] = vv;
    v_out[b * 160 + tid] = vv;
  }
  __syncthreads();
  if (do_update) {
    for (int item = tid; item < 5120; item += 256) {
      int r = item / 10;
      int c = item - r * 10;
      const float* up2 = uhat + b * 81920 + r * 160 + c * 16;
      float a = 0.f;
#pragma unroll
      for (int o = 0; o < 16; o++) a += up2[o] * v_l[c * 16 + o];
      a_buf[b * 5120 + item] = a;
    }
  }
}

__global__ void bupd_k(const float* __restrict__ a_buf, float* __restrict__ bij) {
  int id = blockIdx.x * 256 + threadIdx.x;
  if (id >= 5120) return;
  float s = 0.f;
  for (int b = 0; b < BATCH; b++) s += a_buf[b * 5120 + id];
  bij[id] += s * (1.f / 256.f);
}

__global__ void softmax_b_k(const float* __restrict__ bij, float* __restrict__ c_rc) {
  const int tid = threadIdx.x;
  __shared__ float Ml[10], Sl[10];
  if (tid < 10) {
    float m = -1e30f;
    for (int r = 0; r < 512; r++) m = fmaxf(m, bij[r * 10 + tid]);
    float s = 0.f;
    for (int r = 0; r < 512; r++) s += expf(bij[r * 10 + tid] - m);
    Ml[tid] = m;
    Sl[tid] = s;
  }
  __syncthreads();
  if (tid < 512) {
    for (int c = 0; c < 10; c++)
      c_rc[tid * 10 + c] = expf(bij[tid * 10 + c] - Ml[c]) / Sl[c];
  }
}

__global__ void classes_k(const float* __restrict__ v, float* __restrict__ sel,
                          int* __restrict__ idxb) {
  const int b = threadIdx.x;
  float cl[10], ex[10];
  for (int c = 0; c < 10; c++) {
    float s = 0.f;
    for (int o = 0; o < 16; o++) {
      float e = v[b * 160 + c * 16 + o];
      s += e * e;
    }
    cl[c] = sqrtf(s);
  }
  __shared__ float red[256];
  __shared__ float Mc[10], Sc[10];
  for (int c = 0; c < 10; c++) {
    red[b] = cl[c];
    __syncthreads();
    for (int s = 128; s > 0; s >>= 1) {
      if (b < s) red[b] = fmaxf(red[b], red[b + s]);
      __syncthreads();
    }
    if (b == 0) Mc[c] = red[0];
    __syncthreads();
  }
  for (int c = 0; c < 10; c++) {
    ex[c] = expf(cl[c] - Mc[c]);
    red[b] = ex[c];
    __syncthreads();
    for (int s = 128; s > 0; s >>= 1) {
      if (b < s) red[b] += red[b + s];
      __syncthreads();
    }
    if (b == 0) Sc[c] = red[0];
    __syncthreads();
  }
  float best = ex[0] / Sc[0];
  int bi = 0;
  for (int c = 1; c < 10; c++) {
    float p = ex[c] / Sc[c];
    if (p > best) { best = p; bi = c; }
  }
  idxb[b] = bi;
  for (int o = 0; o < 16; o++) sel[b * 16 + o] = v[b * 160 + bi * 16 + o];
}

__global__ void h1_k(const float* __restrict__ sel, const int* __restrict__ idxb,
                     const float* __restrict__ w1, const float* __restrict__ b1,
                     float* __restrict__ h1) {
  const int b = blockIdx.x;
  const int j = threadIdx.x;
  __shared__ float ssel[16];
  __shared__ int six;
  if (j < 16) ssel[j] = sel[b * 16 + j];
  if (j == 0) six = idxb[b];
  __syncthreads();
  const float* wrow = w1 + j * 160 + six * 16;
  float acc = b1[j];
#pragma unroll
  for (int o = 0; o < 16; o++) acc += ssel[o] * wrow[o];
  h1[b * 512 + j] = fmaxf(acc, 0.f);
}

// ---------------------------------------------------------------------------
// ws layout (float offsets). Peak = 35,717,120 floats = 142.9 MB (same as R1).
//   [0, 20971520)           uhat  (aliases prim partials 8 x 1048576)
//   20971520: h_hi  (ushort, 4718592 floats)   } dead after prim_mfma;
//   25690112: h_lo  (ushort, 4718592 floats)   } small buffers overlay h_hi
//   30408704: wT_hi (ushort, 2654208 floats)
//   33062912: wT_lo (ushort, 2654208 floats)   -> ends 35717120
//   overlay (post-prim, inside h_hi region):
//   x @20971520  v @22020096  bij @22061056  crc @22066176  abuf @22071296
//   sel @23382016  idx @23386112  h1 @23386368  h2 @23517440 (ends 23779584)
// ---------------------------------------------------------------------------
extern "C" void kernel_launch(void* const* d_in, const int* in_sizes, int n_in,
                              void* d_out, int out_size, void* d_ws, size_t ws_size,
                              hipStream_t stream) {
  const float* data    = (const float*)d_in[0];
  const float* conv1_w = (const float*)d_in[1];
  const float* conv1_b = (const float*)d_in[2];
  const float* prim_w  = (const float*)d_in[3];
  const float* prim_b  = (const float*)d_in[4];
  const float* W_digit = (const float*)d_in[5];
  const float* dec_w1  = (const float*)d_in[6];
  const float* dec_b1  = (const float*)d_in[7];
  const float* dec_w2  = (const float*)d_in[8];
  const float* dec_b2  = (const float*)d_in[9];
  const float* dec_w3  = (const float*)d_in[10];
  const float* dec_b3  = (const float*)d_in[11];
  float* out = (float*)d_out;

  float* ws = (float*)d_ws;
  float* uhat = ws;
  float* part = ws;
  unsigned short* h_hi  = (unsigned short*)(ws + 20971520);
  unsigned short* h_lo  = (unsigned short*)(ws + 25690112);
  unsigned short* wT_hi = (unsigned short*)(ws + 30408704);
  unsigned short* wT_lo = (unsigned short*)(ws + 33062912);
  float* x    = ws + 20971520;
  float* v    = ws + 22020096;
  float* bij  = ws + 22061056;
  float* crc  = ws + 22066176;
  float* abuf = ws + 22071296;
  float* sel  = ws + 23382016;
  int*   idxb = (int*)(ws + 23386112);
  float* h1   = ws + 23386368;
  float* h2   = ws + 23517440;

  // 1. split+transpose prim weights to bf16 hi/lo
  transpose_w_k<<<20736, 256, 0, stream>>>(prim_w, wT_hi, wT_lo);

  // 2. conv1 (fp32 GEMM), epilogue writes split-bf16 h
  gemm_k<128, 128, 8, 8, AM_CONV1, EPI_RELU_SPLIT>
      <<<dim3(2, 288, 1), 256, 0, stream>>>(data, conv1_w, conv1_b, nullptr,
                                            36864, 256, 81, 81, h_hi, h_lo);

  // 3. primary-caps conv: split-bf16 MFMA, K-split 8
  prim_mfma_k<<<dim3(2, 32, 8), 256, 0, stream>>>(h_hi, h_lo, wT_hi, wT_lo, part);

  // 4. reduce partials + bias, squash -> x[B,512,8]
  red_squash_k<<<dim3(16, 256), 256, 0, stream>>>(part, prim_b, x);

  // 5. u_hat
  uhat_k<<<512, 256, 0, stream>>>(W_digit, x, uhat);

  // 6. routing
  zero_b_k<<<20, 256, 0, stream>>>(bij);
  route_iter_k<<<256, 256, 0, stream>>>(uhat, crc, v, abuf, 1, 1);
  bupd_k<<<20, 256, 0, stream>>>(abuf, bij);
  softmax_b_k<<<1, 512, 0, stream>>>(bij, crc);
  route_iter_k<<<256, 256, 0, stream>>>(uhat, crc, v, abuf, 0, 1);
  bupd_k<<<20, 256, 0, stream>>>(abuf, bij);
  softmax_b_k<<<1, 512, 0, stream>>>(bij, crc);
  route_iter_k<<<256, 256, 0, stream>>>(uhat, crc, v, nullptr, 0, 0);

  // 7. classes + argmax + mask
  classes_k<<<1, 256, 0, stream>>>(v, sel, idxb);

  // 8. decoder
  h1_k<<<256, 512, 0, stream>>>(sel, idxb, dec_w1, dec_b1, h1);
  gemm_k<128, 128, 8, 8, AM_PLAIN, EPI_RELU>
      <<<dim3(8, 2, 1), 256, 0, stream>>>(h1, dec_w2, dec_b2, h2,
                                          256, 1024, 512, 512, nullptr, nullptr);
  dec3_mfma_k<<<dim3(800, 2, 1), 256, 0, stream>>>(h2, dec_w3, dec_b3, out);
}